// Round 11
// baseline (163.101 us; speedup 1.0000x reference)
//
#include <hip/hip_runtime.h>

typedef _Float16 f16;
typedef _Float16 f16x8 __attribute__((ext_vector_type(8)));
typedef _Float16 f16x4 __attribute__((ext_vector_type(4)));
typedef float f32x4 __attribute__((ext_vector_type(4)));

#define MFMA16(a, b, c) __builtin_amdgcn_mfma_f32_16x16x32_f16((a), (b), (c), 0, 0, 0)

typedef __attribute__((address_space(3))) void lds_void;
typedef const __attribute__((address_space(1))) void g_void;
__device__ __forceinline__ void async_copy16(void* lds, const void* g) {
    __builtin_amdgcn_global_load_lds((g_void*)g, (lds_void*)lds, 16, 0, 0);
}

// ---------------------------------------------------------------------------
// fp32 -> fp16 conversion (x)
__global__ void cvt_x(const float* __restrict__ in, f16* __restrict__ out, int n) {
    int i4 = (blockIdx.x * 256 + threadIdx.x) * 4;
    if (i4 >= n) return;
    float4 v = *reinterpret_cast<const float4*>(in + i4);
    f16x4 o;
    o[0] = (f16)v.x; o[1] = (f16)v.y; o[2] = (f16)v.z; o[3] = (f16)v.w;
    *reinterpret_cast<f16x4*>(out + i4) = o;
}

// ---------------------------------------------------------------------------
// RoPE trig table: tab[pos*32+i] = (cos, sin)(pos * 10000^(-2i/64)).
// Shared across all 16 heads (16x redundant trig removed from rope_v).
__global__ void trig_tab(float2* __restrict__ tab, int Spad) {
    int idx = blockIdx.x * 256 + threadIdx.x;
    if (idx >= Spad * 32) return;
    int pos = idx >> 5, i = idx & 31;
    float inv = exp2f((float)i * (-13.287712379549449f / 32.f));
    float sn, cs;
    __sincosf((float)pos * inv, &sn, &cs);
    tab[idx] = make_float2(cs, sn);
}

// ---------------------------------------------------------------------------
// merged transpose of BOTH weight matrices: fp32 [K][N] -> fp16 [N][K]
// blocks 0..767: Wqkv (1024x3072); blocks 768..1023: Wo (1024x1024)
__global__ void wtrans2(const float* __restrict__ Wqkv, const float* __restrict__ Wo,
                        f16* __restrict__ outQkv, f16* __restrict__ outWo) {
    __shared__ f16 tile[64][65];
    int id = blockIdx.x;
    const float* in; f16* out; int N, bx, by;
    if (id < 768) { in = Wqkv; out = outQkv; N = 3072; bx = id % 48; by = id / 48; }
    else { id -= 768; in = Wo; out = outWo; N = 1024; bx = id % 16; by = id / 16; }
    const int K = 1024;
    int n0 = bx * 64, k0 = by * 64;
    int c = threadIdx.x & 63, rb = threadIdx.x >> 6;
#pragma unroll
    for (int it = 0; it < 16; ++it) {
        int r = rb + it * 4;
        tile[r][c] = (f16)in[(size_t)(k0 + r) * N + n0 + c];
    }
    __syncthreads();
#pragma unroll
    for (int it = 0; it < 16; ++it) {
        int rr = rb + it * 4;
        out[(size_t)(n0 + rr) * K + k0 + c] = tile[c][rr];
    }
}

// ---------------------------------------------------------------------------
// m97-structure GEMM: C[M][N] = A[M][K] @ Bt[N][K]^T + bias.
// 1D grid with XCD-chunked tile order (same-A-panel tiles share an XCD's L2).
#define BM 128
#define BN 128
#define BKK 32
__global__ __launch_bounds__(256) void gemm_tile(
    const f16* __restrict__ A, const f16* __restrict__ Bt,
    const float* __restrict__ bias, f16* __restrict__ Ch, float* __restrict__ Cf,
    int M, int N, int K, int nbx) {
    __shared__ f16 lA[2][BM * BKK];
    __shared__ f16 lB[2][BN * BKK];
    int tid = threadIdx.x;
    int lane = tid & 63, w = tid >> 6;
    int lr = lane & 15, lg = lane >> 4;
    int wm = (w & 1) * 64, wn = (w >> 1) * 64;

    int nwg = gridDim.x, wg = blockIdx.x;
    int tile = ((nwg & 7) == 0) ? ((wg & 7) * (nwg >> 3) + (wg >> 3)) : wg;
    int by = tile / nbx, bx = tile % nbx;

    int srow = tid >> 2;
    int scol = (tid & 3) * 8;
    const f16* ga0 = A  + (size_t)min(by * BM + srow,      M - 1) * K + scol;
    const f16* ga1 = A  + (size_t)min(by * BM + 64 + srow, M - 1) * K + scol;
    const f16* gb0 = Bt + (size_t)min(bx * BN + srow,      N - 1) * K + scol;
    const f16* gb1 = Bt + (size_t)min(bx * BN + 64 + srow, N - 1) * K + scol;

    f32x4 acc[4][4] = {};
    int NT = K / BKK;

#define STAGE(curb, kt) do {                                        \
        int ko = (kt) * BKK;                                        \
        async_copy16(&lA[curb][w * 512],        ga0 + ko);          \
        async_copy16(&lA[curb][2048 + w * 512], ga1 + ko);          \
        async_copy16(&lB[curb][w * 512],        gb0 + ko);          \
        async_copy16(&lB[curb][2048 + w * 512], gb1 + ko);          \
    } while (0)

    STAGE(0, 0);
    __syncthreads();
    int cur = 0;
    for (int kt = 0; kt < NT; ++kt) {
        if (kt + 1 < NT) STAGE(cur ^ 1, kt + 1);
        f16x8 af[4], bf[4];
#pragma unroll
        for (int i = 0; i < 4; ++i) {
            af[i] = *reinterpret_cast<const f16x8*>(&lA[cur][(wm + i * 16 + lr) * BKK + lg * 8]);
            bf[i] = *reinterpret_cast<const f16x8*>(&lB[cur][(wn + i * 16 + lr) * BKK + lg * 8]);
        }
#pragma unroll
        for (int mi = 0; mi < 4; ++mi)
#pragma unroll
            for (int ni = 0; ni < 4; ++ni)
                acc[mi][ni] = MFMA16(af[mi], bf[ni], acc[mi][ni]);
        __syncthreads();
        cur ^= 1;
    }
#undef STAGE

#pragma unroll
    for (int mi = 0; mi < 4; ++mi) {
#pragma unroll
        for (int ni = 0; ni < 4; ++ni) {
            int col = bx * BN + wn + ni * 16 + lr;
            float bv = bias ? bias[col] : 0.f;
#pragma unroll
            for (int r = 0; r < 4; ++r) {
                int row = by * BM + wm + mi * 16 + 4 * lg + r;
                if (row >= M) continue;
                float v = acc[mi][ni][r] + bv;
                if (Ch) Ch[(size_t)row * N + col] = (f16)v;
                else    Cf[(size_t)row * N + col] = v;
            }
        }
    }
}

// ---------------------------------------------------------------------------
// Fused RoPE (q,k -> head-major, Q pre-scaled by 0.125; trig from table) +
// V transpose (vt[b][h][d][pos]).  One block per (64 tokens, head).
__global__ __launch_bounds__(256) void rope_v(
    const f16* __restrict__ qkv, const int* __restrict__ cu,
    const float2* __restrict__ tab, int Bn, int T, int Spad,
    f16* __restrict__ qh2, f16* __restrict__ kh2, f16* __restrict__ vt) {
    __shared__ f16 tile[64][65];
    int h = blockIdx.y;
    int t0 = blockIdx.x * 64;
    int tid = threadIdx.x;
    int c = tid & 63, rb = tid >> 6;
    // V tile load: tile[token][dim]
#pragma unroll
    for (int it = 0; it < 16; ++it) {
        int r = rb + it * 4;
        int t = t0 + r;
        f16 v = (f16)0.f;
        if (t < T) v = qkv[(size_t)t * 3072 + 2048 + h * 64 + c];
        tile[r][c] = v;
    }
    // RoPE: thread handles token t0+(tid>>2), dim group g = tid&3 (dims g*8..+7, +32)
    int tok = t0 + (tid >> 2);
    int g = tid & 3;
    if (tok < T) {
        int b = 0, pos = tok;
        for (int q = 0; q < Bn; ++q) {
            int lo = cu[q], hi = cu[q + 1];
            if (tok >= lo && tok < hi) { b = q; pos = tok - lo; break; }
        }
        const f16* qp = qkv + (size_t)tok * 3072 + h * 64 + g * 8;
        f16x8 q1 = *reinterpret_cast<const f16x8*>(qp);
        f16x8 q2 = *reinterpret_cast<const f16x8*>(qp + 32);
        f16x8 k1 = *reinterpret_cast<const f16x8*>(qp + 1024);
        f16x8 k2 = *reinterpret_cast<const f16x8*>(qp + 1056);
        const float2* tb = tab + pos * 32 + g * 8;
        f16x8 qo1, qo2, ko1, ko2;
#pragma unroll
        for (int e = 0; e < 8; ++e) {
            float2 csn = tb[e];
            float cs = csn.x, sn = csn.y;
            float a = (float)q1[e], bq = (float)q2[e];
            float ka = (float)k1[e], kb = (float)k2[e];
            qo1[e] = (f16)((a * cs - bq * sn) * 0.125f);
            qo2[e] = (f16)((bq * cs + a * sn) * 0.125f);
            ko1[e] = (f16)(ka * cs - kb * sn);
            ko2[e] = (f16)(kb * cs + ka * sn);
        }
        size_t ob = ((size_t)(b * 16 + h) * Spad + pos) * 64 + g * 8;
        *reinterpret_cast<f16x8*>(qh2 + ob)      = qo1;
        *reinterpret_cast<f16x8*>(qh2 + ob + 32) = qo2;
        *reinterpret_cast<f16x8*>(kh2 + ob)      = ko1;
        *reinterpret_cast<f16x8*>(kh2 + ob + 32) = ko2;
    }
    __syncthreads();
    // V scatter: thread's token = t0 + c
    int t = t0 + c;
    int bb = 0, pos2 = -1;
    if (t < T) {
        for (int q = 0; q < Bn; ++q) {
            int lo = cu[q], hi = cu[q + 1];
            if (t >= lo && t < hi) { bb = q; pos2 = t - lo; }
        }
    }
#pragma unroll
    for (int it = 0; it < 16; ++it) {
        int d = rb + it * 4;
        if (pos2 >= 0) vt[((size_t)(bb * 16 + h) * 64 + d) * Spad + pos2] = tile[c][d];
    }
}

// ---------------------------------------------------------------------------
// Flash attention: verified structure, QBLK=16 (one q-tile per wave -> 4096
// blocks = 2x TLP vs QBLK=32; strict simplification of the verified kernel).
// KVBLK=32, swapped-operand MFMA, lane-local softmax, P LDS round-trip with
// barriers, K register double-buffer, V-tile prefetch, bijective XCD-affinity
// remap, longest-first. Q pre-scaled in rope.
__global__ __launch_bounds__(64) void attn_fwd(
    const f16* __restrict__ qh2, const f16* __restrict__ kh2,
    const f16* __restrict__ vt, const int* __restrict__ cu,
    f16* __restrict__ oh, int Spad, int nq, int Bn) {
    int wgid = blockIdx.x;
    int nbh = Bn * 16;
    int b, h, qi;
    if ((nbh & 7) == 0) {
        int xcd = wgid & 7, rest = wgid >> 3, nbh8 = nbh >> 3;
        int bhhi = rest % nbh8;
        qi = (nq - 1) - rest / nbh8;          // longest blocks first
        int bhv = (bhhi << 3) | xcd;
        b = bhv >> 4; h = bhv & 15;
    } else {
        qi = wgid % nq;
        int bhv = wgid / nq;
        b = bhv >> 4; h = bhv & 15;
    }
    int bh = b * 16 + h;
    int s0 = cu[b];
    int len = cu[b + 1] - s0;
    int q0 = qi * 16;
    if (q0 >= len) return;
    int lane = threadIdx.x & 63, lr = lane & 15, lg = lane >> 4;
    __shared__ f16 pl[16][40];   // [q-row][k(32) padded to 40]

    const f16* qbase = qh2 + (size_t)bh * Spad * 64;
    const f16* kbase = kh2 + (size_t)bh * Spad * 64;
    const f16* vbase = vt  + (size_t)bh * 64 * Spad;

    f16x8 qf0, qf1;
    {
        const f16* qp = qbase + (size_t)(q0 + lr) * 64 + 8 * lg;
        qf0 = *reinterpret_cast<const f16x8*>(qp);
        qf1 = *reinterpret_cast<const f16x8*>(qp + 32);
    }
    float mrun = -1e30f, lrun = 0.f;
    f32x4 oacc[4] = {};   // [dt]: row = d_local = 4*lg+r, col = q = lr

    int kend = min(q0 + 16, len);
    int ntk = (kend + 31) >> 5;

    // K register double-buffer: preload tile 0
    f16x8 kf[2][2], kn[2][2];
#pragma unroll
    for (int j = 0; j < 2; ++j) {
        const f16* kp = kbase + (size_t)(16 * j + lr) * 64 + 8 * lg;
        kf[j][0] = *reinterpret_cast<const f16x8*>(kp);
        kf[j][1] = *reinterpret_cast<const f16x8*>(kp + 32);
    }

    for (int kt = 0; kt < ntk; ++kt) {
        int kk0 = kt << 5;
        // V prefetch for this tile (hides L2 latency under softmax)
        f16x8 vf[4];
#pragma unroll
        for (int dt = 0; dt < 4; ++dt)
            vf[dt] = *reinterpret_cast<const f16x8*>(
                vbase + (size_t)(16 * dt + lr) * Spad + kk0 + 8 * lg);
        // S^T tiles: D[row=k_local=4lg+r][col=q=lr]
        f32x4 st[2];
#pragma unroll
        for (int j = 0; j < 2; ++j) {
            f32x4 z = {0, 0, 0, 0};
            z = MFMA16(kf[j][0], qf0, z);
            z = MFMA16(kf[j][1], qf1, z);
            st[j] = z;
        }
        // prefetch next K tile
        if (kt + 1 < ntk) {
#pragma unroll
            for (int j = 0; j < 2; ++j) {
                const f16* kp = kbase + (size_t)(kk0 + 32 + 16 * j + lr) * 64 + 8 * lg;
                kn[j][0] = *reinterpret_cast<const f16x8*>(kp);
                kn[j][1] = *reinterpret_cast<const f16x8*>(kp + 32);
            }
        }
        // online softmax (Q pre-scaled)
        {
            int qr = q0 + lr;
            float sv[2][4];
            float mx = -1e30f;
#pragma unroll
            for (int j = 0; j < 2; ++j)
#pragma unroll
                for (int r = 0; r < 4; ++r) {
                    int kc = kk0 + 16 * j + 4 * lg + r;
                    float v = st[j][r];
                    if (kc > qr || kc >= len) v = -1e30f;
                    sv[j][r] = v;
                    mx = fmaxf(mx, v);
                }
            mx = fmaxf(mx, __shfl_xor(mx, 16, 64));
            mx = fmaxf(mx, __shfl_xor(mx, 32, 64));
            float mnew = fmaxf(mrun, mx);
            float al = __expf(mrun - mnew);
            mrun = mnew;
            float rs = 0.f;
            f16x4 pk0, pk1;
#pragma unroll
            for (int r = 0; r < 4; ++r) {
                float p0 = __expf(sv[0][r] - mnew);
                float p1 = __expf(sv[1][r] - mnew);
                rs += p0 + p1;
                pk0[r] = (f16)p0;
                pk1[r] = (f16)p1;
            }
            rs += __shfl_xor(rs, 16, 64);
            rs += __shfl_xor(rs, 32, 64);
            lrun = lrun * al + rs;
            *reinterpret_cast<f16x4*>(&pl[lr][4 * lg])      = pk0;
            *reinterpret_cast<f16x4*>(&pl[lr][16 + 4 * lg]) = pk1;
#pragma unroll
            for (int dt = 0; dt < 4; ++dt)
#pragma unroll
                for (int r = 0; r < 4; ++r) oacc[dt][r] *= al;
        }
        __syncthreads();
        f16x8 pa = *reinterpret_cast<const f16x8*>(&pl[lr][8 * lg]);
#pragma unroll
        for (int dt = 0; dt < 4; ++dt)
            oacc[dt] = MFMA16(vf[dt], pa, oacc[dt]);
        __syncthreads();
#pragma unroll
        for (int j = 0; j < 2; ++j) {
            kf[j][0] = kn[j][0];
            kf[j][1] = kn[j][1];
        }
    }
    // store: O[q=lr][d=16dt+4lg+r], vectorized 8B per dt
    {
        int qr = q0 + lr;
        if (qr < len) {
            float linv = 1.f / lrun;
            f16* orow = oh + (size_t)(s0 + qr) * 1024 + h * 64;
#pragma unroll
            for (int dt = 0; dt < 4; ++dt) {
                f16x4 ov;
#pragma unroll
                for (int r = 0; r < 4; ++r) ov[r] = (f16)(oacc[dt][r] * linv);
                *reinterpret_cast<f16x4*>(orow + 16 * dt + 4 * lg) = ov;
            }
        }
    }
}

// ---------------------------------------------------------------------------
extern "C" void kernel_launch(void* const* d_in, const int* in_sizes, int n_in,
                              void* d_out, int out_size, void* d_ws, size_t ws_size,
                              hipStream_t stream) {
    const float* x    = (const float*)d_in[0];
    const float* Wqkv = (const float*)d_in[1];
    const float* bqkv = (const float*)d_in[2];
    const float* Wo   = (const float*)d_in[3];
    const float* bo   = (const float*)d_in[4];
    const int*   cu   = (const int*)d_in[5];

    const int Dm = 1024;
    int T  = in_sizes[0] / Dm;
    int Bn = in_sizes[5] - 1;
    int Spad = 1024;  // max_seqlen

    auto al = [](size_t v) { return (v + 255) & ~(size_t)255; };
    char* w = (char*)d_ws;
    size_t off = 0;
    f16* xh     = (f16*)(w + off); off = al(off + (size_t)2 * T * 1024);
    f16* qkvh   = (f16*)(w + off); off = al(off + (size_t)2 * T * 3072);
    f16* wqkvT  = (f16*)(w + off); off = al(off + (size_t)2 * 3072 * 1024);
    f16* woT    = (f16*)(w + off); off = al(off + (size_t)2 * 1024 * 1024);
    f16* qh2    = (f16*)(w + off); off = al(off + (size_t)2 * Bn * 16 * 64 * (size_t)Spad);
    f16* kh2    = (f16*)(w + off); off = al(off + (size_t)2 * Bn * 16 * 64 * (size_t)Spad);
    f16* vtp    = (f16*)(w + off); off = al(off + (size_t)2 * Bn * 16 * 64 * (size_t)Spad);
    f16* ohp    = (f16*)(w + off); off = al(off + (size_t)2 * T * 1024);
    float2* tab = (float2*)(w + off); off = al(off + (size_t)8 * Spad * 32);
    (void)ws_size;

    {
        int n = T * 1024;
        cvt_x<<<(n / 4 + 255) / 256, 256, 0, stream>>>(x, xh, n);
    }
    trig_tab<<<(Spad * 32 + 255) / 256, 256, 0, stream>>>(tab, Spad);
    wtrans2<<<768 + 256, 256, 0, stream>>>(Wqkv, Wo, wqkvT, woT);
    {
        int nbx = 3072 / BN, nby = (T + BM - 1) / BM;
        gemm_tile<<<nbx * nby, 256, 0, stream>>>(xh, wqkvT, bqkv, qkvh, nullptr, T, 3072, 1024, nbx);
    }
    rope_v<<<dim3((T + 63) / 64, 16), 256, 0, stream>>>(qkvh, cu, tab, Bn, T, Spad, qh2, kh2, vtp);
    {
        int nq = Spad / 16;
        int ngrid = nq * 16 * Bn;
        attn_fwd<<<ngrid, 64, 0, stream>>>(qh2, kh2, vtp, cu, ohp, Spad, nq, Bn);
    }
    {
        int nbx = 1024 / BN, nby = (T + BM - 1) / BM;
        gemm_tile<<<nbx * nby, 256, 0, stream>>>(ohp, woT, bo, nullptr, (float*)d_out, T, 1024, 1024, nbx);
    }
}

// Round 12
// 132.614 us; speedup vs baseline: 1.2299x; 1.2299x over previous
//
#include <hip/hip_runtime.h>

typedef _Float16 f16;
typedef _Float16 f16x8 __attribute__((ext_vector_type(8)));
typedef _Float16 f16x4 __attribute__((ext_vector_type(4)));
typedef float f32x4 __attribute__((ext_vector_type(4)));

#define MFMA16(a, b, c) __builtin_amdgcn_mfma_f32_16x16x32_f16((a), (b), (c), 0, 0, 0)

typedef __attribute__((address_space(3))) void lds_void;
typedef const __attribute__((address_space(1))) void g_void;
__device__ __forceinline__ void async_copy16(void* lds, const void* g) {
    __builtin_amdgcn_global_load_lds((g_void*)g, (lds_void*)lds, 16, 0, 0);
}

// ---------------------------------------------------------------------------
// fp32 -> fp16 conversion (x)
__global__ void cvt_x(const float* __restrict__ in, f16* __restrict__ out, int n) {
    int i4 = (blockIdx.x * 256 + threadIdx.x) * 4;
    if (i4 >= n) return;
    float4 v = *reinterpret_cast<const float4*>(in + i4);
    f16x4 o;
    o[0] = (f16)v.x; o[1] = (f16)v.y; o[2] = (f16)v.z; o[3] = (f16)v.w;
    *reinterpret_cast<f16x4*>(out + i4) = o;
}

// ---------------------------------------------------------------------------
// RoPE trig table: tab[pos*32+i] = (cos, sin)(pos * 10000^(-2i/64)).
__global__ void trig_tab(float2* __restrict__ tab, int Spad) {
    int idx = blockIdx.x * 256 + threadIdx.x;
    if (idx >= Spad * 32) return;
    int pos = idx >> 5, i = idx & 31;
    float inv = exp2f((float)i * (-13.287712379549449f / 32.f));
    float sn, cs;
    __sincosf((float)pos * inv, &sn, &cs);
    tab[idx] = make_float2(cs, sn);
}

// ---------------------------------------------------------------------------
// merged transpose of BOTH weight matrices: fp32 [K][N] -> fp16 [N][K]
__global__ void wtrans2(const float* __restrict__ Wqkv, const float* __restrict__ Wo,
                        f16* __restrict__ outQkv, f16* __restrict__ outWo) {
    __shared__ f16 tile[64][65];
    int id = blockIdx.x;
    const float* in; f16* out; int N, bx, by;
    if (id < 768) { in = Wqkv; out = outQkv; N = 3072; bx = id % 48; by = id / 48; }
    else { id -= 768; in = Wo; out = outWo; N = 1024; bx = id % 16; by = id / 16; }
    const int K = 1024;
    int n0 = bx * 64, k0 = by * 64;
    int c = threadIdx.x & 63, rb = threadIdx.x >> 6;
#pragma unroll
    for (int it = 0; it < 16; ++it) {
        int r = rb + it * 4;
        tile[r][c] = (f16)in[(size_t)(k0 + r) * N + n0 + c];
    }
    __syncthreads();
#pragma unroll
    for (int it = 0; it < 16; ++it) {
        int rr = rb + it * 4;
        out[(size_t)(n0 + rr) * K + k0 + c] = tile[c][rr];
    }
}

// ---------------------------------------------------------------------------
// m97-structure GEMM: C[M][N] = A[M][K] @ Bt[N][K]^T + bias.
#define BM 128
#define BN 128
#define BKK 32
__global__ __launch_bounds__(256) void gemm_tile(
    const f16* __restrict__ A, const f16* __restrict__ Bt,
    const float* __restrict__ bias, f16* __restrict__ Ch, float* __restrict__ Cf,
    int M, int N, int K, int nbx) {
    __shared__ f16 lA[2][BM * BKK];
    __shared__ f16 lB[2][BN * BKK];
    int tid = threadIdx.x;
    int lane = tid & 63, w = tid >> 6;
    int lr = lane & 15, lg = lane >> 4;
    int wm = (w & 1) * 64, wn = (w >> 1) * 64;

    int nwg = gridDim.x, wg = blockIdx.x;
    int tile = ((nwg & 7) == 0) ? ((wg & 7) * (nwg >> 3) + (wg >> 3)) : wg;
    int by = tile / nbx, bx = tile % nbx;

    int srow = tid >> 2;
    int scol = (tid & 3) * 8;
    const f16* ga0 = A  + (size_t)min(by * BM + srow,      M - 1) * K + scol;
    const f16* ga1 = A  + (size_t)min(by * BM + 64 + srow, M - 1) * K + scol;
    const f16* gb0 = Bt + (size_t)min(bx * BN + srow,      N - 1) * K + scol;
    const f16* gb1 = Bt + (size_t)min(bx * BN + 64 + srow, N - 1) * K + scol;

    f32x4 acc[4][4] = {};
    int NT = K / BKK;

#define STAGE(curb, kt) do {                                        \
        int ko = (kt) * BKK;                                        \
        async_copy16(&lA[curb][w * 512],        ga0 + ko);          \
        async_copy16(&lA[curb][2048 + w * 512], ga1 + ko);          \
        async_copy16(&lB[curb][w * 512],        gb0 + ko);          \
        async_copy16(&lB[curb][2048 + w * 512], gb1 + ko);          \
    } while (0)

    STAGE(0, 0);
    __syncthreads();
    int cur = 0;
    for (int kt = 0; kt < NT; ++kt) {
        if (kt + 1 < NT) STAGE(cur ^ 1, kt + 1);
        f16x8 af[4], bf[4];
#pragma unroll
        for (int i = 0; i < 4; ++i) {
            af[i] = *reinterpret_cast<const f16x8*>(&lA[cur][(wm + i * 16 + lr) * BKK + lg * 8]);
            bf[i] = *reinterpret_cast<const f16x8*>(&lB[cur][(wn + i * 16 + lr) * BKK + lg * 8]);
        }
#pragma unroll
        for (int mi = 0; mi < 4; ++mi)
#pragma unroll
            for (int ni = 0; ni < 4; ++ni)
                acc[mi][ni] = MFMA16(af[mi], bf[ni], acc[mi][ni]);
        __syncthreads();
        cur ^= 1;
    }
#undef STAGE

#pragma unroll
    for (int mi = 0; mi < 4; ++mi) {
#pragma unroll
        for (int ni = 0; ni < 4; ++ni) {
            int col = bx * BN + wn + ni * 16 + lr;
            float bv = bias ? bias[col] : 0.f;
#pragma unroll
            for (int r = 0; r < 4; ++r) {
                int row = by * BM + wm + mi * 16 + 4 * lg + r;
                if (row >= M) continue;
                float v = acc[mi][ni][r] + bv;
                if (Ch) Ch[(size_t)row * N + col] = (f16)v;
                else    Cf[(size_t)row * N + col] = v;
            }
        }
    }
}

// ---------------------------------------------------------------------------
// Fused RoPE (q,k -> head-major, Q pre-scaled by 0.125; trig from table) +
// V transpose (vt[b][h][d][pos]).
__global__ __launch_bounds__(256) void rope_v(
    const f16* __restrict__ qkv, const int* __restrict__ cu,
    const float2* __restrict__ tab, int Bn, int T, int Spad,
    f16* __restrict__ qh2, f16* __restrict__ kh2, f16* __restrict__ vt) {
    __shared__ f16 tile[64][65];
    int h = blockIdx.y;
    int t0 = blockIdx.x * 64;
    int tid = threadIdx.x;
    int c = tid & 63, rb = tid >> 6;
#pragma unroll
    for (int it = 0; it < 16; ++it) {
        int r = rb + it * 4;
        int t = t0 + r;
        f16 v = (f16)0.f;
        if (t < T) v = qkv[(size_t)t * 3072 + 2048 + h * 64 + c];
        tile[r][c] = v;
    }
    int tok = t0 + (tid >> 2);
    int g = tid & 3;
    if (tok < T) {
        int b = 0, pos = tok;
        for (int q = 0; q < Bn; ++q) {
            int lo = cu[q], hi = cu[q + 1];
            if (tok >= lo && tok < hi) { b = q; pos = tok - lo; break; }
        }
        const f16* qp = qkv + (size_t)tok * 3072 + h * 64 + g * 8;
        f16x8 q1 = *reinterpret_cast<const f16x8*>(qp);
        f16x8 q2 = *reinterpret_cast<const f16x8*>(qp + 32);
        f16x8 k1 = *reinterpret_cast<const f16x8*>(qp + 1024);
        f16x8 k2 = *reinterpret_cast<const f16x8*>(qp + 1056);
        const float2* tb = tab + pos * 32 + g * 8;
        f16x8 qo1, qo2, ko1, ko2;
#pragma unroll
        for (int e = 0; e < 8; ++e) {
            float2 csn = tb[e];
            float cs = csn.x, sn = csn.y;
            float a = (float)q1[e], bq = (float)q2[e];
            float ka = (float)k1[e], kb = (float)k2[e];
            qo1[e] = (f16)((a * cs - bq * sn) * 0.125f);
            qo2[e] = (f16)((bq * cs + a * sn) * 0.125f);
            ko1[e] = (f16)(ka * cs - kb * sn);
            ko2[e] = (f16)(kb * cs + ka * sn);
        }
        size_t ob = ((size_t)(b * 16 + h) * Spad + pos) * 64 + g * 8;
        *reinterpret_cast<f16x8*>(qh2 + ob)      = qo1;
        *reinterpret_cast<f16x8*>(qh2 + ob + 32) = qo2;
        *reinterpret_cast<f16x8*>(kh2 + ob)      = ko1;
        *reinterpret_cast<f16x8*>(kh2 + ob + 32) = ko2;
    }
    __syncthreads();
    int t = t0 + c;
    int bb = 0, pos2 = -1;
    if (t < T) {
        for (int q = 0; q < Bn; ++q) {
            int lo = cu[q], hi = cu[q + 1];
            if (t >= lo && t < hi) { bb = q; pos2 = t - lo; }
        }
    }
#pragma unroll
    for (int it = 0; it < 16; ++it) {
        int d = rb + it * 4;
        if (pos2 >= 0) vt[((size_t)(bb * 16 + h) * 64 + d) * Spad + pos2] = tile[c][d];
    }
}

// ---------------------------------------------------------------------------
// Flash attention v6: 2-wave K-SPLIT. Block = 128 threads = 2 waves, one
// (b,h,32-q-row) tile. Wave w processes k-tiles kt = w, w+2, ... with the
// VERIFIED r10 per-wave compute (QBLK=32, KVBLK=32, swapped operands,
// lane-local softmax, K dbuf, V prefetch). P LDS round-trip is wave-local
// (pl[wave]) ordered by inline s_waitcnt lgkmcnt(0) + sched_barrier fence
// (no in-loop cross-wave barriers). One __syncthreads before the flash merge
// of the two partials. Bijective XCD-affinity remap, longest-first.
__global__ __launch_bounds__(128) void attn_fwd(
    const f16* __restrict__ qh2, const f16* __restrict__ kh2,
    const f16* __restrict__ vt, const int* __restrict__ cu,
    f16* __restrict__ oh, int Spad, int nq, int Bn) {
    int wgid = blockIdx.x;
    int nbh = Bn * 16;
    int b, h, qi;
    if ((nbh & 7) == 0) {
        int xcd = wgid & 7, rest = wgid >> 3, nbh8 = nbh >> 3;
        int bhhi = rest % nbh8;
        qi = (nq - 1) - rest / nbh8;          // longest blocks first
        int bhv = (bhhi << 3) | xcd;
        b = bhv >> 4; h = bhv & 15;
    } else {
        qi = wgid % nq;
        int bhv = wgid / nq;
        b = bhv >> 4; h = bhv & 15;
    }
    int bh = b * 16 + h;
    int s0 = cu[b];
    int len = cu[b + 1] - s0;
    int q0 = qi * 32;
    if (q0 >= len) return;
    int tid = threadIdx.x;
    int wv = tid >> 6;                 // wave 0 or 1
    int lane = tid & 63, lr = lane & 15, lg = lane >> 4;
    __shared__ f16 pl[2][2][16][40];       // [wave][qt][q-row][k pad40]
    __shared__ float mlb[2][2][16];        // wave1 partial: [qt][{m,l}][q]
    __shared__ f32x4 owb[2][4][16][4];     // wave1 partial: [qt][dt][q=lr][lg]

    const f16* qbase = qh2 + (size_t)bh * Spad * 64;
    const f16* kbase = kh2 + (size_t)bh * Spad * 64;
    const f16* vbase = vt  + (size_t)bh * 64 * Spad;

    f16x8 qf[2][2];
#pragma unroll
    for (int qt = 0; qt < 2; ++qt) {
        const f16* qp = qbase + (size_t)(q0 + 16 * qt + lr) * 64 + 8 * lg;
        qf[qt][0] = *reinterpret_cast<const f16x8*>(qp);
        qf[qt][1] = *reinterpret_cast<const f16x8*>(qp + 32);
    }
    float mrun[2] = {-1e30f, -1e30f}, lrun[2] = {0.f, 0.f};
    f32x4 oacc[2][4] = {};   // [qt][dt]: row = d_local = 4*lg+r, col = q = lr

    int kend = min(q0 + 32, len);
    int ntk = (kend + 31) >> 5;        // total tiles; wave wv takes kt=wv,wv+2,..

    // K register double-buffer: preload this wave's first tile (addresses
    // always within the Spad-padded buffer; unused if the wave has no tiles)
    f16x8 kf[2][2], kn[2][2];
#pragma unroll
    for (int j = 0; j < 2; ++j) {
        const f16* kp = kbase + (size_t)(wv * 32 + 16 * j + lr) * 64 + 8 * lg;
        kf[j][0] = *reinterpret_cast<const f16x8*>(kp);
        kf[j][1] = *reinterpret_cast<const f16x8*>(kp + 32);
    }

    for (int kt = wv; kt < ntk; kt += 2) {
        int kk0 = kt << 5;
        // V prefetch for this tile
        f16x8 vf[4];
#pragma unroll
        for (int dt = 0; dt < 4; ++dt)
            vf[dt] = *reinterpret_cast<const f16x8*>(
                vbase + (size_t)(16 * dt + lr) * Spad + kk0 + 8 * lg);
        // S^T tiles: D[row=k_local=4lg+r][col=q=lr]
        f32x4 st[2][2];
#pragma unroll
        for (int qt = 0; qt < 2; ++qt)
#pragma unroll
            for (int j = 0; j < 2; ++j) {
                f32x4 z = {0, 0, 0, 0};
                z = MFMA16(kf[j][0], qf[qt][0], z);
                z = MFMA16(kf[j][1], qf[qt][1], z);
                st[qt][j] = z;
            }
        // prefetch this wave's next K tile (kt+2)
        if (kt + 2 < ntk) {
#pragma unroll
            for (int j = 0; j < 2; ++j) {
                const f16* kp = kbase + (size_t)(kk0 + 64 + 16 * j + lr) * 64 + 8 * lg;
                kn[j][0] = *reinterpret_cast<const f16x8*>(kp);
                kn[j][1] = *reinterpret_cast<const f16x8*>(kp + 32);
            }
        }
        // online softmax (Q pre-scaled); mask on absolute kc
#pragma unroll
        for (int qt = 0; qt < 2; ++qt) {
            int qr = q0 + 16 * qt + lr;
            float sv[2][4];
            float mx = -1e30f;
#pragma unroll
            for (int j = 0; j < 2; ++j)
#pragma unroll
                for (int r = 0; r < 4; ++r) {
                    int kc = kk0 + 16 * j + 4 * lg + r;
                    float v = st[qt][j][r];
                    if (kc > qr || kc >= len) v = -1e30f;
                    sv[j][r] = v;
                    mx = fmaxf(mx, v);
                }
            mx = fmaxf(mx, __shfl_xor(mx, 16, 64));
            mx = fmaxf(mx, __shfl_xor(mx, 32, 64));
            float mnew = fmaxf(mrun[qt], mx);
            float al = __expf(mrun[qt] - mnew);
            mrun[qt] = mnew;
            float rs = 0.f;
            f16x4 pk0, pk1;
#pragma unroll
            for (int r = 0; r < 4; ++r) {
                float p0 = __expf(sv[0][r] - mnew);
                float p1 = __expf(sv[1][r] - mnew);
                rs += p0 + p1;
                pk0[r] = (f16)p0;
                pk1[r] = (f16)p1;
            }
            rs += __shfl_xor(rs, 16, 64);
            rs += __shfl_xor(rs, 32, 64);
            lrun[qt] = lrun[qt] * al + rs;
            *reinterpret_cast<f16x4*>(&pl[wv][qt][lr][4 * lg])      = pk0;
            *reinterpret_cast<f16x4*>(&pl[wv][qt][lr][16 + 4 * lg]) = pk1;
#pragma unroll
            for (int dt = 0; dt < 4; ++dt)
#pragma unroll
                for (int r = 0; r < 4; ++r) oacc[qt][dt][r] *= al;
        }
        // wave-local LDS fence: ds_writes complete before dependent ds_reads;
        // asm memory clobber pins compiler order (rule 18: + sched_barrier).
        asm volatile("s_waitcnt lgkmcnt(0)" ::: "memory");
        __builtin_amdgcn_sched_barrier(0);
        f16x8 pa0 = *reinterpret_cast<const f16x8*>(&pl[wv][0][lr][8 * lg]);
        f16x8 pa1 = *reinterpret_cast<const f16x8*>(&pl[wv][1][lr][8 * lg]);
#pragma unroll
        for (int dt = 0; dt < 4; ++dt) {
            oacc[0][dt] = MFMA16(vf[dt], pa0, oacc[0][dt]);
            oacc[1][dt] = MFMA16(vf[dt], pa1, oacc[1][dt]);
        }
        // prevent next iteration's P-writes from being compiler-hoisted above
        // this iteration's P-reads (DS is in-order per wave in HW).
        asm volatile("" ::: "memory");
#pragma unroll
        for (int j = 0; j < 2; ++j) {
            kf[j][0] = kn[j][0];
            kf[j][1] = kn[j][1];
        }
    }

    // flash merge of the two waves' partials (single uniform barrier)
    if (wv == 1) {
#pragma unroll
        for (int qt = 0; qt < 2; ++qt) {
            if (lg == 0) { mlb[qt][0][lr] = mrun[qt]; mlb[qt][1][lr] = lrun[qt]; }
#pragma unroll
            for (int dt = 0; dt < 4; ++dt)
                owb[qt][dt][lr][lg] = oacc[qt][dt];
        }
    }
    __syncthreads();
    if (wv == 0) {
#pragma unroll
        for (int qt = 0; qt < 2; ++qt) {
            int qr = q0 + 16 * qt + lr;
            if (qr >= len) continue;
            float m1 = mlb[qt][0][lr], l1 = mlb[qt][1][lr];
            float mnew = fmaxf(mrun[qt], m1);
            float a0 = __expf(mrun[qt] - mnew);
            float a1 = __expf(m1 - mnew);
            float linv = 1.f / (lrun[qt] * a0 + l1 * a1);
            f16* orow = oh + (size_t)(s0 + qr) * 1024 + h * 64;
#pragma unroll
            for (int dt = 0; dt < 4; ++dt) {
                f32x4 o1 = owb[qt][dt][lr][lg];
                f16x4 ov;
#pragma unroll
                for (int r = 0; r < 4; ++r)
                    ov[r] = (f16)((oacc[qt][dt][r] * a0 + o1[r] * a1) * linv);
                *reinterpret_cast<f16x4*>(orow + 16 * dt + 4 * lg) = ov;
            }
        }
    }
}

// ---------------------------------------------------------------------------
extern "C" void kernel_launch(void* const* d_in, const int* in_sizes, int n_in,
                              void* d_out, int out_size, void* d_ws, size_t ws_size,
                              hipStream_t stream) {
    const float* x    = (const float*)d_in[0];
    const float* Wqkv = (const float*)d_in[1];
    const float* bqkv = (const float*)d_in[2];
    const float* Wo   = (const float*)d_in[3];
    const float* bo   = (const float*)d_in[4];
    const int*   cu   = (const int*)d_in[5];

    const int Dm = 1024;
    int T  = in_sizes[0] / Dm;
    int Bn = in_sizes[5] - 1;
    int Spad = 1024;  // max_seqlen

    auto al = [](size_t v) { return (v + 255) & ~(size_t)255; };
    char* w = (char*)d_ws;
    size_t off = 0;
    f16* xh     = (f16*)(w + off); off = al(off + (size_t)2 * T * 1024);
    f16* qkvh   = (f16*)(w + off); off = al(off + (size_t)2 * T * 3072);
    f16* wqkvT  = (f16*)(w + off); off = al(off + (size_t)2 * 3072 * 1024);
    f16* woT    = (f16*)(w + off); off = al(off + (size_t)2 * 1024 * 1024);
    f16* qh2    = (f16*)(w + off); off = al(off + (size_t)2 * Bn * 16 * 64 * (size_t)Spad);
    f16* kh2    = (f16*)(w + off); off = al(off + (size_t)2 * Bn * 16 * 64 * (size_t)Spad);
    f16* vtp    = (f16*)(w + off); off = al(off + (size_t)2 * Bn * 16 * 64 * (size_t)Spad);
    f16* ohp    = (f16*)(w + off); off = al(off + (size_t)2 * T * 1024);
    float2* tab = (float2*)(w + off); off = al(off + (size_t)8 * Spad * 32);
    (void)ws_size;

    {
        int n = T * 1024;
        cvt_x<<<(n / 4 + 255) / 256, 256, 0, stream>>>(x, xh, n);
    }
    trig_tab<<<(Spad * 32 + 255) / 256, 256, 0, stream>>>(tab, Spad);
    wtrans2<<<768 + 256, 256, 0, stream>>>(Wqkv, Wo, wqkvT, woT);
    {
        int nbx = 3072 / BN, nby = (T + BM - 1) / BM;
        gemm_tile<<<nbx * nby, 256, 0, stream>>>(xh, wqkvT, bqkv, qkvh, nullptr, T, 3072, 1024, nbx);
    }
    rope_v<<<dim3((T + 63) / 64, 16), 256, 0, stream>>>(qkvh, cu, tab, Bn, T, Spad, qh2, kh2, vtp);
    {
        int nq = Spad / 32;
        int ngrid = nq * 16 * Bn;
        attn_fwd<<<ngrid, 128, 0, stream>>>(qh2, kh2, vtp, cu, ohp, Spad, nq, Bn);
    }
    {
        int nbx = 1024 / BN, nby = (T + BM - 1) / BM;
        gemm_tile<<<nbx * nby, 256, 0, stream>>>(ohp, woT, bo, nullptr, (float*)d_out, T, 1024, 1024, nbx);
    }
}

// Round 13
// 125.292 us; speedup vs baseline: 1.3018x; 1.0584x over previous
//
#include <hip/hip_runtime.h>

typedef _Float16 f16;
typedef _Float16 f16x8 __attribute__((ext_vector_type(8)));
typedef _Float16 f16x4 __attribute__((ext_vector_type(4)));
typedef float f32x4 __attribute__((ext_vector_type(4)));

#define BM 128
#define BN 128
#define BKK 32

#define MFMA16(a, b, c) __builtin_amdgcn_mfma_f32_16x16x32_f16((a), (b), (c), 0, 0, 0)

typedef __attribute__((address_space(3))) void lds_void;
typedef const __attribute__((address_space(1))) void g_void;
__device__ __forceinline__ void async_copy16(void* lds, const void* g) {
    __builtin_amdgcn_global_load_lds((g_void*)g, (lds_void*)lds, 16, 0, 0);
}

// ---------------------------------------------------------------------------
// prep: fused  (a) wtrans of Wqkv+Wo  (b) RoPE trig table  (c) x fp32->fp16.
// Grid partition: [0,1024) wtrans, [1024,1152) trig, [1152, 1152+T) cvt.
__global__ __launch_bounds__(256) void prep(
    const float* __restrict__ x, f16* __restrict__ xh, int T,
    const float* __restrict__ Wqkv, const float* __restrict__ Wo,
    f16* __restrict__ wqkvT, f16* __restrict__ woT,
    float2* __restrict__ tab, int Spad) {
    int id = blockIdx.x;
    int tid = threadIdx.x;
    if (id < 1024) {
        // weight transpose fp32 [K][N] -> fp16 [N][K]
        __shared__ f16 tile[64][65];
        const float* in; f16* out; int N, bx, by;
        if (id < 768) { in = Wqkv; out = wqkvT; N = 3072; bx = id % 48; by = id / 48; }
        else { int j = id - 768; in = Wo; out = woT; N = 1024; bx = j % 16; by = j / 16; }
        const int K = 1024;
        int n0 = bx * 64, k0 = by * 64;
        int c = tid & 63, rb = tid >> 6;
#pragma unroll
        for (int it = 0; it < 16; ++it) {
            int r = rb + it * 4;
            tile[r][c] = (f16)in[(size_t)(k0 + r) * N + n0 + c];
        }
        __syncthreads();
#pragma unroll
        for (int it = 0; it < 16; ++it) {
            int rr = rb + it * 4;
            out[(size_t)(n0 + rr) * K + k0 + c] = tile[c][rr];
        }
    } else if (id < 1152) {
        int idx = (id - 1024) * 256 + tid;
        if (idx < Spad * 32) {
            int pos = idx >> 5, i = idx & 31;
            float inv = exp2f((float)i * (-13.287712379549449f / 32.f));
            float sn, cs;
            __sincosf((float)pos * inv, &sn, &cs);
            tab[idx] = make_float2(cs, sn);
        }
    } else {
        int i4 = ((id - 1152) * 256 + tid) * 4;
        if (i4 < T * 1024) {
            float4 v = *reinterpret_cast<const float4*>(x + i4);
            f16x4 o;
            o[0] = (f16)v.x; o[1] = (f16)v.y; o[2] = (f16)v.z; o[3] = (f16)v.w;
            *reinterpret_cast<f16x4*>(xh + i4) = o;
        }
    }
}

// ---------------------------------------------------------------------------
// shared m97-structure GEMM main loop: fills acc[4][4] for a 128x128 tile.
__device__ __forceinline__ void gemm_core(
    const f16* __restrict__ A, const f16* __restrict__ Bt,
    int M, int N, int K, int bx, int by, int tid,
    f16 lA[2][BM * BKK], f16 lB[2][BN * BKK], f32x4 acc[4][4]) {
    int lane = tid & 63, w = tid >> 6;
    int lr = lane & 15, lg = lane >> 4;
    int wm = (w & 1) * 64, wn = (w >> 1) * 64;
    int srow = tid >> 2;
    int scol = (tid & 3) * 8;
    const f16* ga0 = A  + (size_t)min(by * BM + srow,      M - 1) * K + scol;
    const f16* ga1 = A  + (size_t)min(by * BM + 64 + srow, M - 1) * K + scol;
    const f16* gb0 = Bt + (size_t)min(bx * BN + srow,      N - 1) * K + scol;
    const f16* gb1 = Bt + (size_t)min(bx * BN + 64 + srow, N - 1) * K + scol;
    int NT = K / BKK;
#define STAGE(curb, kt) do {                                        \
        int ko = (kt) * BKK;                                        \
        async_copy16(&lA[curb][w * 512],        ga0 + ko);          \
        async_copy16(&lA[curb][2048 + w * 512], ga1 + ko);          \
        async_copy16(&lB[curb][w * 512],        gb0 + ko);          \
        async_copy16(&lB[curb][2048 + w * 512], gb1 + ko);          \
    } while (0)
    STAGE(0, 0);
    __syncthreads();
    int cur = 0;
    for (int kt = 0; kt < NT; ++kt) {
        if (kt + 1 < NT) STAGE(cur ^ 1, kt + 1);
        f16x8 af[4], bf[4];
#pragma unroll
        for (int i = 0; i < 4; ++i) {
            af[i] = *reinterpret_cast<const f16x8*>(&lA[cur][(wm + i * 16 + lr) * BKK + lg * 8]);
            bf[i] = *reinterpret_cast<const f16x8*>(&lB[cur][(wn + i * 16 + lr) * BKK + lg * 8]);
        }
#pragma unroll
        for (int mi = 0; mi < 4; ++mi)
#pragma unroll
            for (int ni = 0; ni < 4; ++ni)
                acc[mi][ni] = MFMA16(af[mi], bf[ni], acc[mi][ni]);
        __syncthreads();
        cur ^= 1;
    }
#undef STAGE
}

// ---------------------------------------------------------------------------
// QKV GEMM with fused bias + RoPE + head-major scatter epilogue.
// Each wave's 64-col window is entirely inside one section (q/k/v) and one
// head; a lane's four ni-accs hold exactly the RoPE pairs (i, i+32).
__global__ __launch_bounds__(256) void gemm_qkv(
    const f16* __restrict__ A, const f16* __restrict__ Bt,
    const float* __restrict__ bias, const int* __restrict__ cu,
    const float2* __restrict__ tab, int M, int Bn, int Spad,
    f16* __restrict__ qh2, f16* __restrict__ kh2, f16* __restrict__ vt, int nbx) {
    __shared__ f16 lA[2][BM * BKK];
    __shared__ f16 lB[2][BN * BKK];
    int tid = threadIdx.x;
    int nwg = gridDim.x, wg = blockIdx.x;
    int tile = ((nwg & 7) == 0) ? ((wg & 7) * (nwg >> 3) + (wg >> 3)) : wg;
    int by = tile / nbx, bx = tile % nbx;

    f32x4 acc[4][4] = {};
    gemm_core(A, Bt, M, 3072, 1024, bx, by, tid, lA, lB, acc);

    int lane = tid & 63, w = tid >> 6;
    int lr = lane & 15, lg = lane >> 4;
    int wm = (w & 1) * 64, wn = (w >> 1) * 64;
    int colwave = bx * BN + wn;          // multiple of 64
    int sect = colwave >> 10;            // 0=q, 1=k, 2=v
    int h = (colwave & 1023) >> 6;
    float bv[4];
#pragma unroll
    for (int ni = 0; ni < 4; ++ni) bv[ni] = bias[colwave + ni * 16 + lr];

#pragma unroll
    for (int mi = 0; mi < 4; ++mi) {
        int row0 = by * BM + wm + mi * 16 + 4 * lg;
        if (row0 >= M) continue;
        if (sect == 2) {
            // V scatter: vt[(b*16+h)*64+d][pos], d = ni*16+lr
            int b0 = 0, p0 = row0;
            for (int q = 0; q < Bn; ++q) {
                int lo = cu[q], hi = cu[q + 1];
                if (row0 >= lo && row0 < hi) { b0 = q; p0 = row0 - lo; break; }
            }
            bool pack = (row0 + 3 < M) && ((p0 & 3) == 0) && (row0 + 3 < cu[b0 + 1]);
            if (pack) {
                size_t vb = (size_t)(b0 * 16 + h) * 64;
#pragma unroll
                for (int ni = 0; ni < 4; ++ni) {
                    int d = ni * 16 + lr;
                    f16x4 ov;
#pragma unroll
                    for (int r = 0; r < 4; ++r) ov[r] = (f16)(acc[mi][ni][r] + bv[ni]);
                    *reinterpret_cast<f16x4*>(vt + (vb + d) * Spad + p0) = ov;
                }
            } else {
                for (int r = 0; r < 4; ++r) {
                    int row = row0 + r;
                    if (row >= M) break;
                    int b = 0, pos = row;
                    for (int q = 0; q < Bn; ++q) {
                        int lo = cu[q], hi = cu[q + 1];
                        if (row >= lo && row < hi) { b = q; pos = row - lo; break; }
                    }
                    size_t vb = (size_t)(b * 16 + h) * 64;
#pragma unroll
                    for (int ni = 0; ni < 4; ++ni)
                        vt[(vb + ni * 16 + lr) * Spad + pos] = (f16)(acc[mi][ni][r] + bv[ni]);
                }
            }
        } else {
            // RoPE for q (sect 0, pre-scaled 0.125) or k (sect 1)
            float sc = sect == 0 ? 0.125f : 1.f;
            f16* dstbase = sect == 0 ? qh2 : kh2;
            for (int r = 0; r < 4; ++r) {
                int row = row0 + r;
                if (row >= M) break;
                int b = 0, pos = row;
                for (int q = 0; q < Bn; ++q) {
                    int lo = cu[q], hi = cu[q + 1];
                    if (row >= lo && row < hi) { b = q; pos = row - lo; break; }
                }
                const float2* tb = tab + pos * 32;
                f16* dst = dstbase + ((size_t)(b * 16 + h) * Spad + pos) * 64;
#pragma unroll
                for (int p = 0; p < 2; ++p) {
                    int i = p * 16 + lr;
                    float2 csn = tb[i];
                    float v1 = acc[mi][p][r] + bv[p];
                    float v2 = acc[mi][p + 2][r] + bv[p + 2];
                    dst[i]      = (f16)((v1 * csn.x - v2 * csn.y) * sc);
                    dst[i + 32] = (f16)((v2 * csn.x + v1 * csn.y) * sc);
                }
            }
        }
    }
}

// ---------------------------------------------------------------------------
// out-proj GEMM: plain epilogue, fp32 out + bias.
__global__ __launch_bounds__(256) void gemm_out(
    const f16* __restrict__ A, const f16* __restrict__ Bt,
    const float* __restrict__ bias, float* __restrict__ Cf,
    int M, int N, int K, int nbx) {
    __shared__ f16 lA[2][BM * BKK];
    __shared__ f16 lB[2][BN * BKK];
    int tid = threadIdx.x;
    int nwg = gridDim.x, wg = blockIdx.x;
    int tile = ((nwg & 7) == 0) ? ((wg & 7) * (nwg >> 3) + (wg >> 3)) : wg;
    int by = tile / nbx, bx = tile % nbx;

    f32x4 acc[4][4] = {};
    gemm_core(A, Bt, M, N, K, bx, by, tid, lA, lB, acc);

    int lane = tid & 63, w = tid >> 6;
    int lr = lane & 15, lg = lane >> 4;
    int wm = (w & 1) * 64, wn = (w >> 1) * 64;
#pragma unroll
    for (int mi = 0; mi < 4; ++mi) {
#pragma unroll
        for (int ni = 0; ni < 4; ++ni) {
            int col = bx * BN + wn + ni * 16 + lr;
            float bvv = bias[col];
#pragma unroll
            for (int r = 0; r < 4; ++r) {
                int row = by * BM + wm + mi * 16 + 4 * lg + r;
                if (row >= M) continue;
                Cf[(size_t)row * N + col] = acc[mi][ni][r] + bvv;
            }
        }
    }
}

// ---------------------------------------------------------------------------
// Flash attention v6 (r12 verbatim): 2-wave K-SPLIT, QBLK=32, KVBLK=32,
// swapped-operand MFMA, lane-local softmax, wave-local P round-trip with
// inline lgkmcnt fence, flash merge, XCD-affinity remap, longest-first.
__global__ __launch_bounds__(128) void attn_fwd(
    const f16* __restrict__ qh2, const f16* __restrict__ kh2,
    const f16* __restrict__ vt, const int* __restrict__ cu,
    f16* __restrict__ oh, int Spad, int nq, int Bn) {
    int wgid = blockIdx.x;
    int nbh = Bn * 16;
    int b, h, qi;
    if ((nbh & 7) == 0) {
        int xcd = wgid & 7, rest = wgid >> 3, nbh8 = nbh >> 3;
        int bhhi = rest % nbh8;
        qi = (nq - 1) - rest / nbh8;          // longest blocks first
        int bhv = (bhhi << 3) | xcd;
        b = bhv >> 4; h = bhv & 15;
    } else {
        qi = wgid % nq;
        int bhv = wgid / nq;
        b = bhv >> 4; h = bhv & 15;
    }
    int bh = b * 16 + h;
    int s0 = cu[b];
    int len = cu[b + 1] - s0;
    int q0 = qi * 32;
    if (q0 >= len) return;
    int tid = threadIdx.x;
    int wv = tid >> 6;
    int lane = tid & 63, lr = lane & 15, lg = lane >> 4;
    __shared__ f16 pl[2][2][16][40];
    __shared__ float mlb[2][2][16];
    __shared__ f32x4 owb[2][4][16][4];

    const f16* qbase = qh2 + (size_t)bh * Spad * 64;
    const f16* kbase = kh2 + (size_t)bh * Spad * 64;
    const f16* vbase = vt  + (size_t)bh * 64 * Spad;

    f16x8 qf[2][2];
#pragma unroll
    for (int qt = 0; qt < 2; ++qt) {
        const f16* qp = qbase + (size_t)(q0 + 16 * qt + lr) * 64 + 8 * lg;
        qf[qt][0] = *reinterpret_cast<const f16x8*>(qp);
        qf[qt][1] = *reinterpret_cast<const f16x8*>(qp + 32);
    }
    float mrun[2] = {-1e30f, -1e30f}, lrun[2] = {0.f, 0.f};
    f32x4 oacc[2][4] = {};

    int kend = min(q0 + 32, len);
    int ntk = (kend + 31) >> 5;

    f16x8 kf[2][2], kn[2][2];
#pragma unroll
    for (int j = 0; j < 2; ++j) {
        const f16* kp = kbase + (size_t)(wv * 32 + 16 * j + lr) * 64 + 8 * lg;
        kf[j][0] = *reinterpret_cast<const f16x8*>(kp);
        kf[j][1] = *reinterpret_cast<const f16x8*>(kp + 32);
    }

    for (int kt = wv; kt < ntk; kt += 2) {
        int kk0 = kt << 5;
        f16x8 vf[4];
#pragma unroll
        for (int dt = 0; dt < 4; ++dt)
            vf[dt] = *reinterpret_cast<const f16x8*>(
                vbase + (size_t)(16 * dt + lr) * Spad + kk0 + 8 * lg);
        f32x4 st[2][2];
#pragma unroll
        for (int qt = 0; qt < 2; ++qt)
#pragma unroll
            for (int j = 0; j < 2; ++j) {
                f32x4 z = {0, 0, 0, 0};
                z = MFMA16(kf[j][0], qf[qt][0], z);
                z = MFMA16(kf[j][1], qf[qt][1], z);
                st[qt][j] = z;
            }
        if (kt + 2 < ntk) {
#pragma unroll
            for (int j = 0; j < 2; ++j) {
                const f16* kp = kbase + (size_t)(kk0 + 64 + 16 * j + lr) * 64 + 8 * lg;
                kn[j][0] = *reinterpret_cast<const f16x8*>(kp);
                kn[j][1] = *reinterpret_cast<const f16x8*>(kp + 32);
            }
        }
#pragma unroll
        for (int qt = 0; qt < 2; ++qt) {
            int qr = q0 + 16 * qt + lr;
            float sv[2][4];
            float mx = -1e30f;
#pragma unroll
            for (int j = 0; j < 2; ++j)
#pragma unroll
                for (int r = 0; r < 4; ++r) {
                    int kc = kk0 + 16 * j + 4 * lg + r;
                    float v = st[qt][j][r];
                    if (kc > qr || kc >= len) v = -1e30f;
                    sv[j][r] = v;
                    mx = fmaxf(mx, v);
                }
            mx = fmaxf(mx, __shfl_xor(mx, 16, 64));
            mx = fmaxf(mx, __shfl_xor(mx, 32, 64));
            float mnew = fmaxf(mrun[qt], mx);
            float al = __expf(mrun[qt] - mnew);
            mrun[qt] = mnew;
            float rs = 0.f;
            f16x4 pk0, pk1;
#pragma unroll
            for (int r = 0; r < 4; ++r) {
                float p0 = __expf(sv[0][r] - mnew);
                float p1 = __expf(sv[1][r] - mnew);
                rs += p0 + p1;
                pk0[r] = (f16)p0;
                pk1[r] = (f16)p1;
            }
            rs += __shfl_xor(rs, 16, 64);
            rs += __shfl_xor(rs, 32, 64);
            lrun[qt] = lrun[qt] * al + rs;
            *reinterpret_cast<f16x4*>(&pl[wv][qt][lr][4 * lg])      = pk0;
            *reinterpret_cast<f16x4*>(&pl[wv][qt][lr][16 + 4 * lg]) = pk1;
#pragma unroll
            for (int dt = 0; dt < 4; ++dt)
#pragma unroll
                for (int r = 0; r < 4; ++r) oacc[qt][dt][r] *= al;
        }
        asm volatile("s_waitcnt lgkmcnt(0)" ::: "memory");
        __builtin_amdgcn_sched_barrier(0);
        f16x8 pa0 = *reinterpret_cast<const f16x8*>(&pl[wv][0][lr][8 * lg]);
        f16x8 pa1 = *reinterpret_cast<const f16x8*>(&pl[wv][1][lr][8 * lg]);
#pragma unroll
        for (int dt = 0; dt < 4; ++dt) {
            oacc[0][dt] = MFMA16(vf[dt], pa0, oacc[0][dt]);
            oacc[1][dt] = MFMA16(vf[dt], pa1, oacc[1][dt]);
        }
        asm volatile("" ::: "memory");
#pragma unroll
        for (int j = 0; j < 2; ++j) {
            kf[j][0] = kn[j][0];
            kf[j][1] = kn[j][1];
        }
    }

    if (wv == 1) {
#pragma unroll
        for (int qt = 0; qt < 2; ++qt) {
            if (lg == 0) { mlb[qt][0][lr] = mrun[qt]; mlb[qt][1][lr] = lrun[qt]; }
#pragma unroll
            for (int dt = 0; dt < 4; ++dt)
                owb[qt][dt][lr][lg] = oacc[qt][dt];
        }
    }
    __syncthreads();
    if (wv == 0) {
#pragma unroll
        for (int qt = 0; qt < 2; ++qt) {
            int qr = q0 + 16 * qt + lr;
            if (qr >= len) continue;
            float m1 = mlb[qt][0][lr], l1 = mlb[qt][1][lr];
            float mnew = fmaxf(mrun[qt], m1);
            float a0 = __expf(mrun[qt] - mnew);
            float a1 = __expf(m1 - mnew);
            float linv = 1.f / (lrun[qt] * a0 + l1 * a1);
            f16* orow = oh + (size_t)(s0 + qr) * 1024 + h * 64;
#pragma unroll
            for (int dt = 0; dt < 4; ++dt) {
                f32x4 o1 = owb[qt][dt][lr][lg];
                f16x4 ov;
#pragma unroll
                for (int r = 0; r < 4; ++r)
                    ov[r] = (f16)((oacc[qt][dt][r] * a0 + o1[r] * a1) * linv);
                *reinterpret_cast<f16x4*>(orow + 16 * dt + 4 * lg) = ov;
            }
        }
    }
}

// ---------------------------------------------------------------------------
extern "C" void kernel_launch(void* const* d_in, const int* in_sizes, int n_in,
                              void* d_out, int out_size, void* d_ws, size_t ws_size,
                              hipStream_t stream) {
    const float* x    = (const float*)d_in[0];
    const float* Wqkv = (const float*)d_in[1];
    const float* bqkv = (const float*)d_in[2];
    const float* Wo   = (const float*)d_in[3];
    const float* bo   = (const float*)d_in[4];
    const int*   cu   = (const int*)d_in[5];

    const int Dm = 1024;
    int T  = in_sizes[0] / Dm;
    int Bn = in_sizes[5] - 1;
    int Spad = 1024;  // max_seqlen

    auto al = [](size_t v) { return (v + 255) & ~(size_t)255; };
    char* w = (char*)d_ws;
    size_t off = 0;
    f16* xh     = (f16*)(w + off); off = al(off + (size_t)2 * T * 1024);
    f16* wqkvT  = (f16*)(w + off); off = al(off + (size_t)2 * 3072 * 1024);
    f16* woT    = (f16*)(w + off); off = al(off + (size_t)2 * 1024 * 1024);
    f16* qh2    = (f16*)(w + off); off = al(off + (size_t)2 * Bn * 16 * 64 * (size_t)Spad);
    f16* kh2    = (f16*)(w + off); off = al(off + (size_t)2 * Bn * 16 * 64 * (size_t)Spad);
    f16* vtp    = (f16*)(w + off); off = al(off + (size_t)2 * Bn * 16 * 64 * (size_t)Spad);
    f16* ohp    = (f16*)(w + off); off = al(off + (size_t)2 * T * 1024);
    float2* tab = (float2*)(w + off); off = al(off + (size_t)8 * Spad * 32);
    (void)ws_size;

    // 1. prep: weight transposes + trig table + x->fp16
    prep<<<1152 + T, 256, 0, stream>>>(x, xh, T, Wqkv, Wo, wqkvT, woT, tab, Spad);
    // 2. QKV GEMM with fused bias+RoPE+scatter epilogue
    {
        int nbx = 3072 / BN, nby = (T + BM - 1) / BM;
        gemm_qkv<<<nbx * nby, 256, 0, stream>>>(xh, wqkvT, bqkv, cu, tab,
                                                T, Bn, Spad, qh2, kh2, vtp, nbx);
    }
    // 3. attention (r12 verbatim)
    {
        int nq = Spad / 32;
        int ngrid = nq * 16 * Bn;
        attn_fwd<<<ngrid, 128, 0, stream>>>(qh2, kh2, vtp, cu, ohp, Spad, nq, Bn);
    }
    // 4. out-proj GEMM -> fp32 d_out
    {
        int nbx = 1024 / BN, nby = (T + BM - 1) / BM;
        gemm_out<<<nbx * nby, 256, 0, stream>>>(ohp, woT, bo, (float*)d_out,
                                                T, 1024, 1024, nbx);
    }
}

// Round 14
// 119.844 us; speedup vs baseline: 1.3609x; 1.0455x over previous
//
#include <hip/hip_runtime.h>

typedef _Float16 f16;
typedef _Float16 f16x8 __attribute__((ext_vector_type(8)));
typedef _Float16 f16x4 __attribute__((ext_vector_type(4)));
typedef float f32x4 __attribute__((ext_vector_type(4)));

#define BM 128
#define BN 128
#define BKK 32

#define MFMA16(a, b, c) __builtin_amdgcn_mfma_f32_16x16x32_f16((a), (b), (c), 0, 0, 0)

typedef __attribute__((address_space(3))) void lds_void;
typedef const __attribute__((address_space(1))) void g_void;
__device__ __forceinline__ void async_copy16(void* lds, const void* g) {
    __builtin_amdgcn_global_load_lds((g_void*)g, (lds_void*)lds, 16, 0, 0);
}

// ---------------------------------------------------------------------------
// prep: fused (a) wtrans Wqkv+Wo (b) RoPE trig table (c) x fp32->fp16
//       (d) bpos[t] = (seq_id<<16)|pos token table.
// Grid: [0,1024) wtrans, [1024,1152) trig, [1152,1152+T) cvt, rest bpos.
__global__ __launch_bounds__(256) void prep(
    const float* __restrict__ x, f16* __restrict__ xh, int T,
    const float* __restrict__ Wqkv, const float* __restrict__ Wo,
    f16* __restrict__ wqkvT, f16* __restrict__ woT,
    float2* __restrict__ tab, int Spad,
    const int* __restrict__ cu, int Bn, int* __restrict__ bpos) {
    int id = blockIdx.x;
    int tid = threadIdx.x;
    if (id < 1024) {
        __shared__ f16 tile[64][65];
        const float* in; f16* out; int N, bx, by;
        if (id < 768) { in = Wqkv; out = wqkvT; N = 3072; bx = id % 48; by = id / 48; }
        else { int j = id - 768; in = Wo; out = woT; N = 1024; bx = j % 16; by = j / 16; }
        const int K = 1024;
        int n0 = bx * 64, k0 = by * 64;
        int c = tid & 63, rb = tid >> 6;
#pragma unroll
        for (int it = 0; it < 16; ++it) {
            int r = rb + it * 4;
            tile[r][c] = (f16)in[(size_t)(k0 + r) * N + n0 + c];
        }
        __syncthreads();
#pragma unroll
        for (int it = 0; it < 16; ++it) {
            int rr = rb + it * 4;
            out[(size_t)(n0 + rr) * K + k0 + c] = tile[c][rr];
        }
    } else if (id < 1152) {
        int idx = (id - 1024) * 256 + tid;
        if (idx < Spad * 32) {
            int pos = idx >> 5, i = idx & 31;
            float inv = exp2f((float)i * (-13.287712379549449f / 32.f));
            float sn, cs;
            __sincosf((float)pos * inv, &sn, &cs);
            tab[idx] = make_float2(cs, sn);
        }
    } else if (id < 1152 + T) {
        int i4 = ((id - 1152) * 256 + tid) * 4;
        if (i4 < T * 1024) {
            float4 v = *reinterpret_cast<const float4*>(x + i4);
            f16x4 o;
            o[0] = (f16)v.x; o[1] = (f16)v.y; o[2] = (f16)v.z; o[3] = (f16)v.w;
            *reinterpret_cast<f16x4*>(xh + i4) = o;
        }
    } else {
        int t = (id - 1152 - T) * 256 + tid;
        if (t < T) {
            int b = 0, pos = t;
            for (int q = 0; q < Bn; ++q) {
                int lo = cu[q], hi = cu[q + 1];
                if (t >= lo && t < hi) { b = q; pos = t - lo; break; }
            }
            bpos[t] = (b << 16) | pos;
        }
    }
}

// ---------------------------------------------------------------------------
// shared m97-structure GEMM main loop: fills acc[4][4] for a 128x128 tile.
__device__ __forceinline__ void gemm_core(
    const f16* __restrict__ A, const f16* __restrict__ Bt,
    int M, int N, int K, int bx, int by, int tid,
    f16 lA[2][BM * BKK], f16 lB[2][BN * BKK], f32x4 acc[4][4]) {
    int lane = tid & 63, w = tid >> 6;
    int lr = lane & 15, lg = lane >> 4;
    int wm = (w & 1) * 64, wn = (w >> 1) * 64;
    int srow = tid >> 2;
    int scol = (tid & 3) * 8;
    const f16* ga0 = A  + (size_t)min(by * BM + srow,      M - 1) * K + scol;
    const f16* ga1 = A  + (size_t)min(by * BM + 64 + srow, M - 1) * K + scol;
    const f16* gb0 = Bt + (size_t)min(bx * BN + srow,      N - 1) * K + scol;
    const f16* gb1 = Bt + (size_t)min(bx * BN + 64 + srow, N - 1) * K + scol;
    int NT = K / BKK;
#define STAGE(curb, kt) do {                                        \
        int ko = (kt) * BKK;                                        \
        async_copy16(&lA[curb][w * 512],        ga0 + ko);          \
        async_copy16(&lA[curb][2048 + w * 512], ga1 + ko);          \
        async_copy16(&lB[curb][w * 512],        gb0 + ko);          \
        async_copy16(&lB[curb][2048 + w * 512], gb1 + ko);          \
    } while (0)
    STAGE(0, 0);
    __syncthreads();
    int cur = 0;
    for (int kt = 0; kt < NT; ++kt) {
        if (kt + 1 < NT) STAGE(cur ^ 1, kt + 1);
        f16x8 af[4], bf[4];
#pragma unroll
        for (int i = 0; i < 4; ++i) {
            af[i] = *reinterpret_cast<const f16x8*>(&lA[cur][(wm + i * 16 + lr) * BKK + lg * 8]);
            bf[i] = *reinterpret_cast<const f16x8*>(&lB[cur][(wn + i * 16 + lr) * BKK + lg * 8]);
        }
#pragma unroll
        for (int mi = 0; mi < 4; ++mi)
#pragma unroll
            for (int ni = 0; ni < 4; ++ni)
                acc[mi][ni] = MFMA16(af[mi], bf[ni], acc[mi][ni]);
        __syncthreads();
        cur ^= 1;
    }
#undef STAGE
}

// ---------------------------------------------------------------------------
// QKV GEMM with fused bias + RoPE + head-major scatter epilogue (bpos table).
__global__ __launch_bounds__(256) void gemm_qkv(
    const f16* __restrict__ A, const f16* __restrict__ Bt,
    const float* __restrict__ bias, const int* __restrict__ bpos,
    const float2* __restrict__ tab, int M, int Spad,
    f16* __restrict__ qh2, f16* __restrict__ kh2, f16* __restrict__ vt, int nbx) {
    __shared__ f16 lA[2][BM * BKK];
    __shared__ f16 lB[2][BN * BKK];
    int tid = threadIdx.x;
    int nwg = gridDim.x, wg = blockIdx.x;
    int tile = ((nwg & 7) == 0) ? ((wg & 7) * (nwg >> 3) + (wg >> 3)) : wg;
    int by = tile / nbx, bx = tile % nbx;

    f32x4 acc[4][4] = {};
    gemm_core(A, Bt, M, 3072, 1024, bx, by, tid, lA, lB, acc);

    int lane = tid & 63, w = tid >> 6;
    int lr = lane & 15, lg = lane >> 4;
    int wm = (w & 1) * 64, wn = (w >> 1) * 64;
    int colwave = bx * BN + wn;          // multiple of 64
    int sect = colwave >> 10;            // 0=q, 1=k, 2=v
    int h = (colwave & 1023) >> 6;
    float bv[4];
#pragma unroll
    for (int ni = 0; ni < 4; ++ni) bv[ni] = bias[colwave + ni * 16 + lr];

#pragma unroll
    for (int mi = 0; mi < 4; ++mi) {
        int row0 = by * BM + wm + mi * 16 + 4 * lg;
        if (row0 >= M) continue;
        if (sect == 2) {
            int v0 = bpos[row0];
            int b0 = v0 >> 16, p0 = v0 & 0xffff;
            bool pack = (row0 + 3 < M) && ((p0 & 3) == 0) && ((bpos[row0 + 3] >> 16) == b0);
            if (pack) {
                size_t vb = (size_t)(b0 * 16 + h) * 64;
#pragma unroll
                for (int ni = 0; ni < 4; ++ni) {
                    int d = ni * 16 + lr;
                    f16x4 ov;
#pragma unroll
                    for (int r = 0; r < 4; ++r) ov[r] = (f16)(acc[mi][ni][r] + bv[ni]);
                    *reinterpret_cast<f16x4*>(vt + (vb + d) * Spad + p0) = ov;
                }
            } else {
                for (int r = 0; r < 4; ++r) {
                    int row = row0 + r;
                    if (row >= M) break;
                    int v = bpos[row];
                    int b = v >> 16, pos = v & 0xffff;
                    size_t vb = (size_t)(b * 16 + h) * 64;
#pragma unroll
                    for (int ni = 0; ni < 4; ++ni)
                        vt[(vb + ni * 16 + lr) * Spad + pos] = (f16)(acc[mi][ni][r] + bv[ni]);
                }
            }
        } else {
            float sc = sect == 0 ? 0.125f : 1.f;
            f16* dstbase = sect == 0 ? qh2 : kh2;
            for (int r = 0; r < 4; ++r) {
                int row = row0 + r;
                if (row >= M) break;
                int v = bpos[row];
                int b = v >> 16, pos = v & 0xffff;
                const float2* tb = tab + pos * 32;
                f16* dst = dstbase + ((size_t)(b * 16 + h) * Spad + pos) * 64;
#pragma unroll
                for (int p = 0; p < 2; ++p) {
                    int i = p * 16 + lr;
                    float2 csn = tb[i];
                    float v1 = acc[mi][p][r] + bv[p];
                    float v2 = acc[mi][p + 2][r] + bv[p + 2];
                    dst[i]      = (f16)((v1 * csn.x - v2 * csn.y) * sc);
                    dst[i + 32] = (f16)((v2 * csn.x + v1 * csn.y) * sc);
                }
            }
        }
    }
}

// ---------------------------------------------------------------------------
// out-proj GEMM: plain epilogue, fp32 out + bias.
__global__ __launch_bounds__(256) void gemm_out(
    const f16* __restrict__ A, const f16* __restrict__ Bt,
    const float* __restrict__ bias, float* __restrict__ Cf,
    int M, int N, int K, int nbx) {
    __shared__ f16 lA[2][BM * BKK];
    __shared__ f16 lB[2][BN * BKK];
    int tid = threadIdx.x;
    int nwg = gridDim.x, wg = blockIdx.x;
    int tile = ((nwg & 7) == 0) ? ((wg & 7) * (nwg >> 3) + (wg >> 3)) : wg;
    int by = tile / nbx, bx = tile % nbx;

    f32x4 acc[4][4] = {};
    gemm_core(A, Bt, M, N, K, bx, by, tid, lA, lB, acc);

    int lane = tid & 63, w = tid >> 6;
    int lr = lane & 15, lg = lane >> 4;
    int wm = (w & 1) * 64, wn = (w >> 1) * 64;
#pragma unroll
    for (int mi = 0; mi < 4; ++mi) {
#pragma unroll
        for (int ni = 0; ni < 4; ++ni) {
            int col = bx * BN + wn + ni * 16 + lr;
            float bvv = bias[col];
#pragma unroll
            for (int r = 0; r < 4; ++r) {
                int row = by * BM + wm + mi * 16 + 4 * lg + r;
                if (row >= M) continue;
                Cf[(size_t)row * N + col] = acc[mi][ni][r] + bvv;
            }
        }
    }
}

// ---------------------------------------------------------------------------
// Flash attention v7: 4-wave K-SPLIT (validated axis from r12's 2-wave).
// Block = 256 threads = 4 waves, one (b,h,32-q-row) tile. Wave wv processes
// k-tiles kt = wv, wv+4, ... with the verified inner loop (QBLK=32, KVBLK=32,
// swapped operands, lane-local softmax, K dbuf, V prefetch, wave-local P
// round-trip with inline lgkmcnt fence). Flash merge of 4 partials at end.
// Bijective XCD-affinity remap, longest-first.
__global__ __launch_bounds__(256) void attn_fwd(
    const f16* __restrict__ qh2, const f16* __restrict__ kh2,
    const f16* __restrict__ vt, const int* __restrict__ cu,
    f16* __restrict__ oh, int Spad, int nq, int Bn) {
    int wgid = blockIdx.x;
    int nbh = Bn * 16;
    int b, h, qi;
    if ((nbh & 7) == 0) {
        int xcd = wgid & 7, rest = wgid >> 3, nbh8 = nbh >> 3;
        int bhhi = rest % nbh8;
        qi = (nq - 1) - rest / nbh8;          // longest blocks first
        int bhv = (bhhi << 3) | xcd;
        b = bhv >> 4; h = bhv & 15;
    } else {
        qi = wgid % nq;
        int bhv = wgid / nq;
        b = bhv >> 4; h = bhv & 15;
    }
    int bh = b * 16 + h;
    int s0 = cu[b];
    int len = cu[b + 1] - s0;
    int q0 = qi * 32;
    if (q0 >= len) return;
    int tid = threadIdx.x;
    int wv = tid >> 6;                     // wave 0..3
    int lane = tid & 63, lr = lane & 15, lg = lane >> 4;
    __shared__ f16 pl[4][2][16][40];       // [wave][qt][q-row][k pad40]
    __shared__ float mlb[3][2][2][16];     // [wave-1][qt][{m,l}][q]
    __shared__ f32x4 owb[3][2][4][16][4];  // [wave-1][qt][dt][q=lr][lg]

    const f16* qbase = qh2 + (size_t)bh * Spad * 64;
    const f16* kbase = kh2 + (size_t)bh * Spad * 64;
    const f16* vbase = vt  + (size_t)bh * 64 * Spad;

    f16x8 qf[2][2];
#pragma unroll
    for (int qt = 0; qt < 2; ++qt) {
        const f16* qp = qbase + (size_t)(q0 + 16 * qt + lr) * 64 + 8 * lg;
        qf[qt][0] = *reinterpret_cast<const f16x8*>(qp);
        qf[qt][1] = *reinterpret_cast<const f16x8*>(qp + 32);
    }
    float mrun[2] = {-1e30f, -1e30f}, lrun[2] = {0.f, 0.f};
    f32x4 oacc[2][4] = {};

    int kend = min(q0 + 32, len);
    int ntk = (kend + 31) >> 5;            // wave wv takes kt = wv, wv+4, ...

    f16x8 kf[2][2], kn[2][2];
#pragma unroll
    for (int j = 0; j < 2; ++j) {
        const f16* kp = kbase + (size_t)(wv * 32 + 16 * j + lr) * 64 + 8 * lg;
        kf[j][0] = *reinterpret_cast<const f16x8*>(kp);
        kf[j][1] = *reinterpret_cast<const f16x8*>(kp + 32);
    }

    for (int kt = wv; kt < ntk; kt += 4) {
        int kk0 = kt << 5;
        f16x8 vf[4];
#pragma unroll
        for (int dt = 0; dt < 4; ++dt)
            vf[dt] = *reinterpret_cast<const f16x8*>(
                vbase + (size_t)(16 * dt + lr) * Spad + kk0 + 8 * lg);
        f32x4 st[2][2];
#pragma unroll
        for (int qt = 0; qt < 2; ++qt)
#pragma unroll
            for (int j = 0; j < 2; ++j) {
                f32x4 z = {0, 0, 0, 0};
                z = MFMA16(kf[j][0], qf[qt][0], z);
                z = MFMA16(kf[j][1], qf[qt][1], z);
                st[qt][j] = z;
            }
        if (kt + 4 < ntk) {
#pragma unroll
            for (int j = 0; j < 2; ++j) {
                const f16* kp = kbase + (size_t)(kk0 + 128 + 16 * j + lr) * 64 + 8 * lg;
                kn[j][0] = *reinterpret_cast<const f16x8*>(kp);
                kn[j][1] = *reinterpret_cast<const f16x8*>(kp + 32);
            }
        }
#pragma unroll
        for (int qt = 0; qt < 2; ++qt) {
            int qr = q0 + 16 * qt + lr;
            float sv[2][4];
            float mx = -1e30f;
#pragma unroll
            for (int j = 0; j < 2; ++j)
#pragma unroll
                for (int r = 0; r < 4; ++r) {
                    int kc = kk0 + 16 * j + 4 * lg + r;
                    float v = st[qt][j][r];
                    if (kc > qr || kc >= len) v = -1e30f;
                    sv[j][r] = v;
                    mx = fmaxf(mx, v);
                }
            mx = fmaxf(mx, __shfl_xor(mx, 16, 64));
            mx = fmaxf(mx, __shfl_xor(mx, 32, 64));
            float mnew = fmaxf(mrun[qt], mx);
            float al = __expf(mrun[qt] - mnew);
            mrun[qt] = mnew;
            float rs = 0.f;
            f16x4 pk0, pk1;
#pragma unroll
            for (int r = 0; r < 4; ++r) {
                float p0 = __expf(sv[0][r] - mnew);
                float p1 = __expf(sv[1][r] - mnew);
                rs += p0 + p1;
                pk0[r] = (f16)p0;
                pk1[r] = (f16)p1;
            }
            rs += __shfl_xor(rs, 16, 64);
            rs += __shfl_xor(rs, 32, 64);
            lrun[qt] = lrun[qt] * al + rs;
            *reinterpret_cast<f16x4*>(&pl[wv][qt][lr][4 * lg])      = pk0;
            *reinterpret_cast<f16x4*>(&pl[wv][qt][lr][16 + 4 * lg]) = pk1;
#pragma unroll
            for (int dt = 0; dt < 4; ++dt)
#pragma unroll
                for (int r = 0; r < 4; ++r) oacc[qt][dt][r] *= al;
        }
        asm volatile("s_waitcnt lgkmcnt(0)" ::: "memory");
        __builtin_amdgcn_sched_barrier(0);
        f16x8 pa0 = *reinterpret_cast<const f16x8*>(&pl[wv][0][lr][8 * lg]);
        f16x8 pa1 = *reinterpret_cast<const f16x8*>(&pl[wv][1][lr][8 * lg]);
#pragma unroll
        for (int dt = 0; dt < 4; ++dt) {
            oacc[0][dt] = MFMA16(vf[dt], pa0, oacc[0][dt]);
            oacc[1][dt] = MFMA16(vf[dt], pa1, oacc[1][dt]);
        }
        asm volatile("" ::: "memory");
#pragma unroll
        for (int j = 0; j < 2; ++j) {
            kf[j][0] = kn[j][0];
            kf[j][1] = kn[j][1];
        }
    }

    // flash merge of 4 waves' partials
    if (wv > 0) {
#pragma unroll
        for (int qt = 0; qt < 2; ++qt) {
            if (lg == 0) {
                mlb[wv - 1][qt][0][lr] = mrun[qt];
                mlb[wv - 1][qt][1][lr] = lrun[qt];
            }
#pragma unroll
            for (int dt = 0; dt < 4; ++dt)
                owb[wv - 1][qt][dt][lr][lg] = oacc[qt][dt];
        }
    }
    __syncthreads();
    if (wv == 0) {
#pragma unroll
        for (int qt = 0; qt < 2; ++qt) {
            int qr = q0 + 16 * qt + lr;
            if (qr >= len) continue;
            float m = mrun[qt];
#pragma unroll
            for (int i = 0; i < 3; ++i) m = fmaxf(m, mlb[i][qt][0][lr]);
            float a0 = __expf(mrun[qt] - m);
            float lsum = lrun[qt] * a0;
            float ai[3];
#pragma unroll
            for (int i = 0; i < 3; ++i) {
                ai[i] = __expf(mlb[i][qt][0][lr] - m);
                lsum += mlb[i][qt][1][lr] * ai[i];
            }
            float linv = 1.f / lsum;
            f16* orow = oh + (size_t)(s0 + qr) * 1024 + h * 64;
#pragma unroll
            for (int dt = 0; dt < 4; ++dt) {
                f16x4 ov;
#pragma unroll
                for (int r = 0; r < 4; ++r) {
                    float o = oacc[qt][dt][r] * a0;
#pragma unroll
                    for (int i = 0; i < 3; ++i) o += owb[i][qt][dt][lr][lg][r] * ai[i];
                    ov[r] = (f16)(o * linv);
                }
                *reinterpret_cast<f16x4*>(orow + 16 * dt + 4 * lg) = ov;
            }
        }
    }
}

// ---------------------------------------------------------------------------
extern "C" void kernel_launch(void* const* d_in, const int* in_sizes, int n_in,
                              void* d_out, int out_size, void* d_ws, size_t ws_size,
                              hipStream_t stream) {
    const float* x    = (const float*)d_in[0];
    const float* Wqkv = (const float*)d_in[1];
    const float* bqkv = (const float*)d_in[2];
    const float* Wo   = (const float*)d_in[3];
    const float* bo   = (const float*)d_in[4];
    const int*   cu   = (const int*)d_in[5];

    const int Dm = 1024;
    int T  = in_sizes[0] / Dm;
    int Bn = in_sizes[5] - 1;
    int Spad = 1024;  // max_seqlen

    auto al = [](size_t v) { return (v + 255) & ~(size_t)255; };
    char* w = (char*)d_ws;
    size_t off = 0;
    f16* xh     = (f16*)(w + off); off = al(off + (size_t)2 * T * 1024);
    f16* wqkvT  = (f16*)(w + off); off = al(off + (size_t)2 * 3072 * 1024);
    f16* woT    = (f16*)(w + off); off = al(off + (size_t)2 * 1024 * 1024);
    f16* qh2    = (f16*)(w + off); off = al(off + (size_t)2 * Bn * 16 * 64 * (size_t)Spad);
    f16* kh2    = (f16*)(w + off); off = al(off + (size_t)2 * Bn * 16 * 64 * (size_t)Spad);
    f16* vtp    = (f16*)(w + off); off = al(off + (size_t)2 * Bn * 16 * 64 * (size_t)Spad);
    f16* ohp    = (f16*)(w + off); off = al(off + (size_t)2 * T * 1024);
    float2* tab = (float2*)(w + off); off = al(off + (size_t)8 * Spad * 32);
    int* bpos   = (int*)(w + off);   off = al(off + (size_t)4 * T);
    (void)ws_size;

    // 1. prep: weight transposes + trig table + x->fp16 + bpos table
    {
        int nb = 1152 + T + (T + 255) / 256;
        prep<<<nb, 256, 0, stream>>>(x, xh, T, Wqkv, Wo, wqkvT, woT, tab, Spad,
                                     cu, Bn, bpos);
    }
    // 2. QKV GEMM with fused bias+RoPE+scatter epilogue
    {
        int nbx = 3072 / BN, nby = (T + BM - 1) / BM;
        gemm_qkv<<<nbx * nby, 256, 0, stream>>>(xh, wqkvT, bqkv, bpos, tab,
                                                T, Spad, qh2, kh2, vtp, nbx);
    }
    // 3. attention (4-wave K-split)
    {
        int nq = Spad / 32;
        int ngrid = nq * 16 * Bn;
        attn_fwd<<<ngrid, 256, 0, stream>>>(qh2, kh2, vtp, cu, ohp, Spad, nq, Bn);
    }
    // 4. out-proj GEMM -> fp32 d_out
    {
        int nbx = 1024 / BN, nby = (T + BM - 1) / BM;
        gemm_out<<<nbx * nby, 256, 0, stream>>>(ohp, woT, bo, (float*)d_out,
                                                T, 1024, 1024, nbx);
    }
}